// Round 1
// baseline (2294.423 us; speedup 1.0000x reference)
//
#include <hip/hip_runtime.h>
#include <math.h>

// GNN: GatedGraphConv(4 steps) + BN/ReLU + mean-pool + MLP head. fp32 baseline.
// Algebraic fusion: C_i = ggc_w[i] @ gru_wih^T so per-step work is
//   s = scatter_add(h[src] -> dst)  (CSR gather, no atomics)
//   gi = s @ C_i + bih ; gh = h @ Whh^T + bhh ; GRU elementwise.

#define EPSV 1e-5f

__device__ __forceinline__ float fsig(float x){
  return 1.0f/(1.0f+__expf(-x));
}
__device__ __forceinline__ float ftanh(float x){
  float ax = fabsf(x);
  float e = __expf(-2.0f*ax);
  float r = (1.0f-e)/(1.0f+e);
  return copysignf(r, x);
}

__global__ void k_zero(float* __restrict__ p, int n){
  int i = blockIdx.x*256+threadIdx.x;
  if (i<n) p[i]=0.0f;
}

// WtIn[k*128+j] = W_in[j*128+k]
__global__ void k_prep_wint(const float* __restrict__ Win, float* __restrict__ Wt){
  int i = blockIdx.x*256+threadIdx.x;
  if (i>=16384) return;
  int k=i>>7, j=i&127;
  Wt[k*128+j] = Win[j*128+k];
}
// HW[k*384+c] = whh[c*128+k]   (c = gate*128 + j)
__global__ void k_prep_hw(const float* __restrict__ whh, float* __restrict__ HW){
  int i = blockIdx.x*256+threadIdx.x;
  if (i>=49152) return;
  int k=i/384, c=i%384;
  HW[k*384+c] = whh[c*128+k];
}
// CW[s][k*384+c] = sum_m ggc[s][k][m] * wih[c][m]
__global__ void k_prep_cw(const float* __restrict__ ggc, const float* __restrict__ wih, float* __restrict__ CW){
  int i = blockIdx.x*256+threadIdx.x;
  if (i>=196608) return;
  int s=i/49152; int r=i%49152; int k=r/384; int c=r%384;
  const float* g = ggc + s*16384 + k*128;
  const float* w = wih + c*128;
  float acc=0.f;
  for (int m=0;m<128;m++) acc += g[m]*w[m];
  CW[i]=acc;
}
// W1cT[j*128+o] = W1[o][j] + W1[o][128+j]   (pooled = [mean,mean] concat)
__global__ void k_prep_w1c(const float* __restrict__ W1, float* __restrict__ W1cT){
  int i = blockIdx.x*256+threadIdx.x;
  if (i>=16384) return;
  int j=i>>7, o=i&127;
  W1cT[j*128+o] = W1[o*256+j] + W1[o*256+128+j];
}

// t = x @ W_in^T + b_in, with fused per-column sum/sumsq partials (64-way)
__global__ __launch_bounds__(256,2) void k_gemm_in(
    const float* __restrict__ x, const float* __restrict__ Wt, const float* __restrict__ bin,
    float* __restrict__ X, float* __restrict__ sumP, float* __restrict__ sqP, int N)
{
  __shared__ float xl[32][128];
  __shared__ float red[2][128];
  int t=threadIdx.x, wave=t>>6, lane=t&63;
  int nbase = blockIdx.x*32;
  for (int q=0;q<8;q++){
    int nl=wave*8+q; int n=nbase+nl;
    float2 v=make_float2(0.f,0.f);
    if (n<N) v = *(const float2*)&x[(size_t)n*128+lane*2];
    *(float2*)&xl[nl][lane*2] = v;
  }
  __syncthreads();
  int j=t&127, half=t>>7, nb=half*16;
  float acc[16];
  #pragma unroll
  for (int q=0;q<16;q++) acc[q]=0.f;
  for (int k=0;k<128;k+=2){
    float w0 = Wt[k*128+j];
    float w1 = Wt[(k+1)*128+j];
    #pragma unroll
    for (int q=0;q<16;q++){
      float2 xv = *(const float2*)&xl[nb+q][k];
      acc[q] += xv.x*w0 + xv.y*w1;
    }
  }
  float bv = bin[j];
  float ts=0.f, tq=0.f;
  #pragma unroll
  for (int q=0;q<16;q++){
    int n=nbase+nb+q;
    if (n<N){
      float tv=acc[q]+bv;
      X[(size_t)n*128+j]=tv;
      ts+=tv; tq+=tv*tv;
    }
  }
  int p = (blockIdx.x&63)*128+j;
  red[half][j]=ts; __syncthreads();
  if (half==0) atomicAdd(&sumP[p], red[0][j]+red[1][j]);
  __syncthreads();
  red[half][j]=tq; __syncthreads();
  if (half==0) atomicAdd(&sqP[p], red[0][j]+red[1][j]);
}

// reduce P partials -> scale/shift for BN
__global__ void k_bn_fin(const float* __restrict__ sumP, const float* __restrict__ sqP, int P, float invcnt,
                         const float* __restrict__ g, const float* __restrict__ b,
                         float* __restrict__ sc, float* __restrict__ sh){
  int j = threadIdx.x;
  if (j>=128) return;
  float s=0.f,q=0.f;
  for (int p=0;p<P;p++){ s+=sumP[p*128+j]; q+=sqP[p*128+j]; }
  float mu = s*invcnt;
  float var = fmaxf(q*invcnt - mu*mu, 0.f);
  float scale = g[j]*rsqrtf(var+EPSV);
  sc[j]=scale; sh[j]=b[j]-mu*scale;
}

// h0 = relu(t*sc+sh)
__global__ void k_apply_bn1(const float4* __restrict__ X, const float* __restrict__ sc,
                            const float* __restrict__ sh, float4* __restrict__ h0, int total4){
  int i = blockIdx.x*256+threadIdx.x;
  if (i>=total4) return;
  float4 t = X[i];
  int j0 = (i*4)&127;
  float4 s = *(const float4*)&sc[j0];
  float4 b = *(const float4*)&sh[j0];
  float4 o;
  o.x = fmaxf(t.x*s.x+b.x, 0.f);
  o.y = fmaxf(t.y*s.y+b.y, 0.f);
  o.z = fmaxf(t.z*s.z+b.z, 0.f);
  o.w = fmaxf(t.w*s.w+b.w, 0.f);
  h0[i]=o;
}

// ---- CSR build (rows = dst, cols = src) ----
__global__ void k_hist(const int* __restrict__ dst, int* __restrict__ deg, int E){
  int e = blockIdx.x*256+threadIdx.x;
  if (e<E) atomicAdd(&deg[dst[e]], 1);
}
__global__ void k_scan1(const int* __restrict__ deg, int* __restrict__ rowptr, int* __restrict__ bsum, int N){
  __shared__ int tmp[256];
  int t=threadIdx.x; int n=blockIdx.x*256+t;
  int v = (n<N)?deg[n]:0;
  tmp[t]=v;
  __syncthreads();
  for (int o=1;o<256;o<<=1){
    int add = (t>=o)? tmp[t-o] : 0;
    __syncthreads();
    tmp[t]+=add;
    __syncthreads();
  }
  if (n<N) rowptr[n+1]=tmp[t];
  if (t==255) bsum[blockIdx.x]=tmp[255];
}
__global__ void k_scan2(int* bsum, int nb, int* rowptr){
  if (threadIdx.x==0 && blockIdx.x==0){
    int run=0;
    for (int i=0;i<nb;i++){ int v=bsum[i]; bsum[i]=run; run+=v; }
    rowptr[0]=0;
  }
}
__global__ void k_scan3(int* rowptr, const int* bsum, int N){
  int n = blockIdx.x*256+threadIdx.x;
  if (n<N) rowptr[n+1] += bsum[blockIdx.x];
}
__global__ void k_curcopy(const int* __restrict__ rowptr, int* __restrict__ cur, int N){
  int n = blockIdx.x*256+threadIdx.x;
  if (n<N) cur[n]=rowptr[n];
}
__global__ void k_fill(const int* __restrict__ ei, int* __restrict__ cur, int* __restrict__ col, int E){
  int e = blockIdx.x*256+threadIdx.x;
  if (e<E){
    int d = ei[E+e];
    int pos = atomicAdd(&cur[d],1);
    col[pos]=ei[e];
  }
}

// Fused: aggregate (CSR gather-sum of hin rows) + gi/gh GEMM + GRU update.
// Block = 32 nodes. LDS sh[node][k][{s,h}]; GEMM reads are wave-uniform broadcasts.
__global__ __launch_bounds__(256,2) void k_gru(
    const float* __restrict__ hin, float* __restrict__ hout,
    const int* __restrict__ rowptr, const int* __restrict__ col,
    const float* __restrict__ CW, const float* __restrict__ HW,
    const float* __restrict__ bih, const float* __restrict__ bhh, int N)
{
  __shared__ float sh[32][128][2];
  int t=threadIdx.x, wave=t>>6, lane=t&63;
  int nbase = blockIdx.x*32;
  // Phase A: stage h rows + aggregate s rows (each wave: 8 nodes, lane owns 2 cols)
  for (int q=0;q<8;q++){
    int nl = wave*8+q; int n = nbase+nl;
    float2 sa = make_float2(0.f,0.f);
    float2 hv = make_float2(0.f,0.f);
    if (n<N){
      hv = *(const float2*)&hin[(size_t)n*128 + lane*2];
      int e = rowptr[n], r1 = rowptr[n+1];
      for (; e+3<r1; e+=4){
        int s0=col[e], s1=col[e+1], s2=col[e+2], s3=col[e+3];
        float2 v0 = *(const float2*)&hin[(size_t)s0*128 + lane*2];
        float2 v1 = *(const float2*)&hin[(size_t)s1*128 + lane*2];
        float2 v2 = *(const float2*)&hin[(size_t)s2*128 + lane*2];
        float2 v3 = *(const float2*)&hin[(size_t)s3*128 + lane*2];
        sa.x += (v0.x+v1.x)+(v2.x+v3.x);
        sa.y += (v0.y+v1.y)+(v2.y+v3.y);
      }
      for (; e<r1; e++){
        int s0=col[e];
        float2 v0 = *(const float2*)&hin[(size_t)s0*128 + lane*2];
        sa.x += v0.x; sa.y += v0.y;
      }
    }
    sh[nl][lane*2  ][0]=sa.x;
    sh[nl][lane*2+1][0]=sa.y;
    sh[nl][lane*2  ][1]=hv.x;
    sh[nl][lane*2+1][1]=hv.y;
  }
  __syncthreads();
  // Phase B: thread owns column j for 16 nodes; 6 accumulators per node.
  int j=t&127, half=t>>7, nb=half*16;
  float air[16],aiz[16],ain[16],ahr[16],ahz[16],ahn[16];
  #pragma unroll
  for (int q=0;q<16;q++){ air[q]=0.f;aiz[q]=0.f;ain[q]=0.f;ahr[q]=0.f;ahz[q]=0.f;ahn[q]=0.f; }
  #pragma unroll 2
  for (int k=0;k<128;k++){
    float wir = CW[k*384 + j];
    float wiz = CW[k*384 + 128 + j];
    float win = CW[k*384 + 256 + j];
    float whr = HW[k*384 + j];
    float whz = HW[k*384 + 128 + j];
    float whn = HW[k*384 + 256 + j];
    #pragma unroll
    for (int q=0;q<16;q++){
      float2 svhv = *(const float2*)&sh[nb+q][k][0];
      air[q] += svhv.x*wir; aiz[q] += svhv.x*wiz; ain[q] += svhv.x*win;
      ahr[q] += svhv.y*whr; ahz[q] += svhv.y*whz; ahn[q] += svhv.y*whn;
    }
  }
  float br=bih[j], bz=bih[128+j], bn_=bih[256+j];
  float cr=bhh[j], cz=bhh[128+j], cn=bhh[256+j];
  #pragma unroll
  for (int q=0;q<16;q++){
    int n = nbase+nb+q;
    if (n<N){
      float r = fsig((air[q]+br) + (ahr[q]+cr));
      float z = fsig((aiz[q]+bz) + (ahz[q]+cz));
      float nn = ftanh((ain[q]+bn_) + r*(ahn[q]+cn));
      float hold = hin[(size_t)n*128 + j];
      hout[(size_t)n*128 + j] = (1.f-z)*nn + z*hold;
    }
  }
}

// column sum/sumsq of A[N,128] into 64-way partials
__global__ void k_colstats(const float* __restrict__ A, int N, float* __restrict__ sumP, float* __restrict__ sqP){
  __shared__ float red[2][128];
  int t=threadIdx.x, j=t&127, half=t>>7;
  int n0 = blockIdx.x*128;
  float s=0.f,q=0.f;
  for (int r=half; r<128; r+=2){
    int n=n0+r; if (n>=N) break;
    float v = A[(size_t)n*128+j];
    s+=v; q+=v*v;
  }
  int p = (blockIdx.x&63)*128+j;
  red[half][j]=s; __syncthreads();
  if (half==0) atomicAdd(&sumP[p], red[0][j]+red[1][j]);
  __syncthreads();
  red[half][j]=q; __syncthreads();
  if (half==0) atomicAdd(&sqP[p], red[0][j]+red[1][j]);
}

// hf = relu(bn2(h)+skip), run-length pooled into pool[g][j] (batch is sorted)
__global__ void k_bn2_pool(const float* __restrict__ hfin, const float* __restrict__ h0,
                           const int* __restrict__ batch, const float* __restrict__ sc,
                           const float* __restrict__ sh, float* __restrict__ pool, int N){
  int t=threadIdx.x, j=t&127, half=t>>7;
  int n0 = blockIdx.x*256 + half*128;
  float scv=sc[j], shv=sh[j];
  int curg=-1; float acc=0.f;
  for (int r=0;r<128;r++){
    int n=n0+r; if (n>=N) break;
    int g = batch[n];
    float v = fmaxf(hfin[(size_t)n*128+j]*scv+shv + h0[(size_t)n*128+j], 0.f);
    if (g!=curg){
      if (curg>=0) atomicAdd(&pool[curg*128+j], acc);
      curg=g; acc=0.f;
    }
    acc+=v;
  }
  if (curg>=0) atomicAdd(&pool[curg*128+j], acc);
}

__global__ void k_cnt(const int* __restrict__ batch, float* __restrict__ cntf, int N){
  int n = blockIdx.x*256+threadIdx.x;
  if (n<N) atomicAdd(&cntf[batch[n]], 1.0f);
}

// t3[g][o] = b1[o] + sum_j mean[g][j]*W1cT[j][o]; + BN3 stat atomics
__global__ void k_head1(const float* __restrict__ pool, const float* __restrict__ cntf,
                        const float* __restrict__ W1cT, const float* __restrict__ b1,
                        float* __restrict__ t3, float* __restrict__ sum3, float* __restrict__ sq3){
  __shared__ float mean[128];
  int g=blockIdx.x, o=threadIdx.x;
  float inv = 1.0f/fmaxf(cntf[g],1.0f);
  mean[o] = pool[g*128+o]*inv;
  __syncthreads();
  float acc=0.f;
  for (int jj=0;jj<128;jj++) acc += mean[jj]*W1cT[jj*128+o];
  float v = acc + b1[o];
  t3[g*128+o]=v;
  atomicAdd(&sum3[o], v);
  atomicAdd(&sq3[o], v*v);
}

// y1 = relu(bn3(t3)); out = y1 @ W2^T + b2
__global__ void k_head2(const float* __restrict__ t3, const float* __restrict__ sc,
                        const float* __restrict__ sh, const float* __restrict__ W2,
                        const float* __restrict__ b2, float* __restrict__ out){
  __shared__ float y[128];
  int g=blockIdx.x, o=threadIdx.x;
  float v = fmaxf(t3[g*128+o]*sc[o]+sh[o], 0.f);
  y[o]=v; __syncthreads();
  if (o<2){
    float acc=b2[o];
    for (int k=0;k<128;k++) acc += y[k]*W2[o*128+k];
    out[g*2+o]=acc;
  }
}

extern "C" void kernel_launch(void* const* d_in, const int* in_sizes, int n_in,
                              void* d_out, int out_size, void* d_ws, size_t ws_size,
                              hipStream_t stream){
  (void)n_in; (void)ws_size;
  const float* x    = (const float*)d_in[0];
  const int*   ei   = (const int*)d_in[1];
  const int*   batch= (const int*)d_in[2];
  const float* W_in = (const float*)d_in[3];
  const float* b_in = (const float*)d_in[4];
  const float* bn1_g= (const float*)d_in[5];
  const float* bn1_b= (const float*)d_in[6];
  const float* ggc  = (const float*)d_in[7];
  const float* wih  = (const float*)d_in[8];
  const float* whh  = (const float*)d_in[9];
  const float* bih  = (const float*)d_in[10];
  const float* bhh  = (const float*)d_in[11];
  const float* bn2_g= (const float*)d_in[12];
  const float* bn2_b= (const float*)d_in[13];
  const float* W1   = (const float*)d_in[14];
  const float* b1   = (const float*)d_in[15];
  const float* bn3_g= (const float*)d_in[16];
  const float* bn3_b= (const float*)d_in[17];
  const float* W2   = (const float*)d_in[18];
  const float* b2   = (const float*)d_in[19];
  float* out = (float*)d_out;

  int N = in_sizes[0]/128;
  int E = in_sizes[1]/2;
  int G = out_size/2;

  char* ws = (char*)d_ws;
  size_t off=0;
  auto alloc=[&](size_t bytes)->char*{
    char* p = ws+off; off = (off+bytes+255) & ~(size_t)255; return p;
  };
  float* X   = (float*)alloc((size_t)N*128*4);   // t, then ping-pong h
  float* h0  = (float*)alloc((size_t)N*128*4);   // skip
  float* hA  = (float*)alloc((size_t)N*128*4);   // ping-pong h
  float* CW  = (float*)alloc((size_t)4*49152*4);
  float* HW  = (float*)alloc((size_t)49152*4);
  float* WtIn= (float*)alloc((size_t)16384*4);
  float* W1cT= (float*)alloc((size_t)16384*4);
  int* rowptr= (int*)alloc((size_t)(N+1)*4);
  int* cur   = (int*)alloc((size_t)N*4);
  int* col   = (int*)alloc((size_t)E*4);
  int* bsum  = (int*)alloc((size_t)4096*4);
  float* t3  = (float*)alloc((size_t)G*128*4);
  float* sc1 = (float*)alloc(512); float* sh1 = (float*)alloc(512);
  float* sc2 = (float*)alloc(512); float* sh2 = (float*)alloc(512);
  float* sc3 = (float*)alloc(512); float* sh3 = (float*)alloc(512);
  // --- zero region (contiguous) ---
  char* zstart = ws+off;
  int*   deg  = (int*)alloc((size_t)N*4);
  float* sumP1= (float*)alloc((size_t)64*128*4);
  float* sqP1 = (float*)alloc((size_t)64*128*4);
  float* sumP2= (float*)alloc((size_t)64*128*4);
  float* sqP2 = (float*)alloc((size_t)64*128*4);
  float* sum3 = (float*)alloc(512);
  float* sq3  = (float*)alloc(512);
  float* pool = (float*)alloc((size_t)G*128*4);
  float* cntf = (float*)alloc((size_t)G*4);
  char* zend = ws+off;
  int zwords = (int)((zend - zstart)/4);

  int nbScan = (N+255)/256;
  int gridN32 = (N+31)/32;

  k_zero<<<(zwords+255)/256,256,0,stream>>>((float*)zstart, zwords);
  k_prep_wint<<<64,256,0,stream>>>(W_in, WtIn);
  k_prep_hw<<<192,256,0,stream>>>(whh, HW);
  k_prep_cw<<<768,256,0,stream>>>(ggc, wih, CW);
  k_prep_w1c<<<64,256,0,stream>>>(W1, W1cT);

  k_gemm_in<<<gridN32,256,0,stream>>>(x, WtIn, b_in, X, sumP1, sqP1, N);
  k_bn_fin<<<1,128,0,stream>>>(sumP1, sqP1, 64, 1.0f/(float)N, bn1_g, bn1_b, sc1, sh1);
  k_apply_bn1<<<(N*128/4+255)/256,256,0,stream>>>((const float4*)X, sc1, sh1, (float4*)h0, N*128/4);

  k_hist<<<(E+255)/256,256,0,stream>>>(ei+E, deg, E);
  k_scan1<<<nbScan,256,0,stream>>>(deg, rowptr, bsum, N);
  k_scan2<<<1,1,0,stream>>>(bsum, nbScan, rowptr);
  k_scan3<<<nbScan,256,0,stream>>>(rowptr, bsum, N);
  k_curcopy<<<nbScan,256,0,stream>>>(rowptr, cur, N);
  k_fill<<<(E+255)/256,256,0,stream>>>(ei, cur, col, E);

  // 4 GRU steps, ping-pong h0 -> X -> hA -> X -> hA
  k_gru<<<gridN32,256,0,stream>>>(h0, X,  rowptr, col, CW+0*49152, HW, bih, bhh, N);
  k_gru<<<gridN32,256,0,stream>>>(X,  hA, rowptr, col, CW+1*49152, HW, bih, bhh, N);
  k_gru<<<gridN32,256,0,stream>>>(hA, X,  rowptr, col, CW+2*49152, HW, bih, bhh, N);
  k_gru<<<gridN32,256,0,stream>>>(X,  hA, rowptr, col, CW+3*49152, HW, bih, bhh, N);

  k_colstats<<<(N+127)/128,256,0,stream>>>(hA, N, sumP2, sqP2);
  k_bn_fin<<<1,128,0,stream>>>(sumP2, sqP2, 64, 1.0f/(float)N, bn2_g, bn2_b, sc2, sh2);
  k_cnt<<<(N+255)/256,256,0,stream>>>(batch, cntf, N);
  k_bn2_pool<<<(N+255)/256,256,0,stream>>>(hA, h0, batch, sc2, sh2, pool, N);

  k_head1<<<G,128,0,stream>>>(pool, cntf, W1cT, b1, t3, sum3, sq3);
  k_bn_fin<<<1,128,0,stream>>>(sum3, sq3, 1, 1.0f/(float)G, bn3_g, bn3_b, sc3, sh3);
  k_head2<<<G,128,0,stream>>>(t3, sc3, sh3, W2, b2, out);
}